// Round 8
// baseline (519.895 us; speedup 1.0000x reference)
//
#include <hip/hip_runtime.h>

#define NF 128
#define NH 64
#define NC 40
#define BSHIFT 10                 // bucket = dst >> 10  (1024 nodes/bucket)
#define NB 98                     // ceil(100000 / 1024)
#define BIN_T 2048                // edges per k_bin block
#define BSTRIDE 20480             // fixed slots per bucket (mean 16327, sigma 128 -> 32-sigma safe)

typedef __attribute__((ext_vector_type(8))) short short8;
typedef __attribute__((ext_vector_type(4))) float float4v;

__device__ __forceinline__ unsigned rotl32(unsigned v, int s) { return (v << s) | (v >> (32 - s)); }

__device__ __forceinline__ unsigned short f2bf(float f) {   // fp32 -> bf16 RNE
  unsigned u = __float_as_uint(f);
  return (unsigned short)((u + 0x7FFFu + ((u >> 16) & 1u)) >> 16);
}
__device__ __forceinline__ float bf2f(unsigned short b) {
  return __uint_as_float(((unsigned)b) << 16);
}

// threefry2x32, key(0,42), partitionable path: bits = x0^x1 of counter (0, idx).
__device__ __forceinline__ unsigned threefry_bits(unsigned idx) {
  const unsigned k0 = 0u, k1 = 42u;
  const unsigned k2x = 0u ^ 42u ^ 0x1BD11BDAu;
  unsigned x0 = 0u, x1 = idx;
  x0 += k0; x1 += k1;
  x0 += x1; x1 = rotl32(x1, 13); x1 ^= x0;
  x0 += x1; x1 = rotl32(x1, 15); x1 ^= x0;
  x0 += x1; x1 = rotl32(x1, 26); x1 ^= x0;
  x0 += x1; x1 = rotl32(x1, 6);  x1 ^= x0;
  x0 += k1; x1 += k2x + 1u;
  x0 += x1; x1 = rotl32(x1, 17); x1 ^= x0;
  x0 += x1; x1 = rotl32(x1, 29); x1 ^= x0;
  x0 += x1; x1 = rotl32(x1, 16); x1 ^= x0;
  x0 += x1; x1 = rotl32(x1, 24); x1 ^= x0;
  x0 += k2x; x1 += k0 + 2u;
  x0 += x1; x1 = rotl32(x1, 13); x1 ^= x0;
  x0 += x1; x1 = rotl32(x1, 15); x1 ^= x0;
  x0 += x1; x1 = rotl32(x1, 26); x1 ^= x0;
  x0 += x1; x1 = rotl32(x1, 6);  x1 ^= x0;
  x0 += k0; x1 += k1 + 3u;
  x0 += x1; x1 = rotl32(x1, 17); x1 ^= x0;
  x0 += x1; x1 = rotl32(x1, 29); x1 ^= x0;
  x0 += x1; x1 = rotl32(x1, 16); x1 ^= x0;
  x0 += x1; x1 = rotl32(x1, 24); x1 ^= x0;
  x0 += k1; x1 += k2x + 4u;
  x0 += x1; x1 = rotl32(x1, 13); x1 ^= x0;
  x0 += x1; x1 = rotl32(x1, 15); x1 ^= x0;
  x0 += x1; x1 = rotl32(x1, 26); x1 ^= x0;
  x0 += x1; x1 = rotl32(x1, 6);  x1 ^= x0;
  x0 += k2x; x1 += k0 + 5u;
  return x0 ^ x1;
}

// Bin edges into fixed-stride buckets; packed word = (src<<10) | (dst & 1023).
// Blocks >= nbin do the one-shot weight prep (W1 -> bf16 [c][k]; W2 -> bf16 padded [c<48][k<64]).
__global__ __launch_bounds__(256) void k_bin(const int* __restrict__ src, const int* __restrict__ dst,
                                             int* __restrict__ gcur, unsigned* __restrict__ binned,
                                             const float* __restrict__ W1, const float* __restrict__ W2,
                                             unsigned short* __restrict__ Wt1b, unsigned short* __restrict__ Wt2b,
                                             int nE, int nbin) {
  int t = threadIdx.x;
  if (blockIdx.x >= nbin) {                 // weight-prep blocks
    int id = (blockIdx.x - nbin) * 256 + t;
    if (id < NF * NH) {
      int k = id >> 6, c = id & 63;
      Wt1b[c * NF + k] = f2bf(W1[id]);
    } else if (id < NF * NH + 48 * NH) {
      int id2 = id - NF * NH;
      int c = id2 >> 6, k = id2 & 63;
      Wt2b[c * NH + k] = (c < NC) ? f2bf(W2[k * NC + c]) : 0;
    }
    return;
  }
  __shared__ int h[NB];
  __shared__ int off[NB];
  int b0 = blockIdx.x * BIN_T;
  int b1 = b0 + BIN_T; if (b1 > nE) b1 = nE;
  if (t < NB) h[t] = 0;
  __syncthreads();
  for (int e = b0 + t; e < b1; e += 256)
    atomicAdd(&h[dst[e] >> BSHIFT], 1);
  __syncthreads();
  if (t < NB && h[t] > 0) off[t] = t * BSTRIDE + atomicAdd(&gcur[t], h[t]);
  __syncthreads();
  for (int e = b0 + t; e < b1; e += 256) {
    int s = src[e], d = dst[e];
    int p = atomicAdd(&off[d >> BSHIFT], 1);
    binned[p] = ((unsigned)s << BSHIFT) | (unsigned)(d & ((1 << BSHIFT) - 1));
  }
}

// Per-bucket: node degree hist -> shfl-scan -> rpd (packed start<<11|deg) + dis + degree-class
// histogram (for the balance sort), then place csrc.
__global__ __launch_bounds__(1024) void k_fillb(const unsigned* __restrict__ binned, const int* __restrict__ gcur,
                                                unsigned* __restrict__ rpd, float* __restrict__ dis,
                                                int* __restrict__ csrc, int* __restrict__ clscnt, int n) {
  __shared__ int hist[1024];
  __shared__ int wsum[16];
  __shared__ int clsh[64];
  int b = blockIdx.x;
  int base = b << BSHIFT;
  int t = threadIdx.x;
  int lo = b * BSTRIDE, hi = lo + gcur[b];
  hist[t] = 0;
  if (t < 64) clsh[t] = 0;
  __syncthreads();
  for (int e = lo + t; e < hi; e += 1024)
    atomicAdd(&hist[binned[e] & 1023u], 1);
  __syncthreads();
  int v = hist[t];
  // wave-level inclusive scan (64 lanes, no barriers)
  int sv = v;
#pragma unroll
  for (int off = 1; off < 64; off <<= 1) {
    int u = __shfl_up(sv, off);
    if ((t & 63) >= off) sv += u;
  }
  int wid = t >> 6;
  if ((t & 63) == 63) wsum[wid] = sv;
  __syncthreads();
  if (t < 16) {                       // scan the 16 wave totals -> exclusive
    int ws = wsum[t];
    int sws = ws;
#pragma unroll
    for (int off = 1; off < 16; off <<= 1) {
      int u = __shfl_up(sws, off);
      if (t >= off) sws += u;
    }
    wsum[t] = sws - ws;
  }
  __syncthreads();
  int excl = sv - v + wsum[wid];
  if (base + t < n) {
    rpd[base + t] = ((unsigned)(lo + excl) << 11) | (unsigned)v;
    dis[base + t] = rsqrtf((float)(v + 1));
    atomicAdd(&clsh[v > 63 ? 63 : v], 1);
  }
  __syncthreads();
  if (t < 64 && clsh[t]) atomicAdd(&clscnt[t], clsh[t]);
  hist[t] = lo + excl;
  __syncthreads();
  for (int e = lo + t; e < hi; e += 1024) {
    unsigned p = binned[e];
    int pos = atomicAdd(&hist[p & 1023u], 1);
    csrc[pos] = (int)(p >> BSHIFT);
  }
}

// y1 = bf16( dis[i] * (dropout(x) @ W1) ) via MFMA bf16.  16 nodes/block, 4 waves.
// Block 0 additionally scans the 64 degree-class counters into clsbase (safe: clscnt
// was finalized by the previous kernel; clsbase is only read by the next kernel).
__global__ __launch_bounds__(256) void k_xw(const float* __restrict__ x, const unsigned short* __restrict__ Wt1b,
                                            const float* __restrict__ dis, unsigned short* __restrict__ y1b,
                                            const int* __restrict__ clscnt, int* __restrict__ clsbase, int n) {
  __shared__ unsigned short Ws[NH * 136];
  __shared__ unsigned short xs[16 * 136];
  int t = threadIdx.x;
  if (blockIdx.x == 0 && t < 64) {
    int c = clscnt[t];
    int s = c;
#pragma unroll
    for (int off = 1; off < 64; off <<= 1) {
      int u = __shfl_up(s, off);
      if (t >= off) s += u;
    }
    clsbase[t] = s - c;               // exclusive prefix
  }
  int nodeBase = blockIdx.x * 16;
  for (int id = t; id < NH * 16; id += 256) {
    int c = id >> 4, kc = id & 15;
    *(short8*)&Ws[c * 136 + kc * 8] = *(const short8*)&Wt1b[c * NF + kc * 8];
  }
  {
    int nloc = t >> 4, kbase = (t & 15) * 8;
    int ebase = (nodeBase + nloc) * NF + kbase;
    const float4* xp = (const float4*)x;
    float4 a = xp[(ebase >> 2)];
    float4 b = xp[(ebase >> 2) + 1];
    float v[8] = {a.x, a.y, a.z, a.w, b.x, b.y, b.z, b.w};
#pragma unroll
    for (int q = 0; q < 8; ++q) {
      unsigned idx = (unsigned)(ebase + q);
      bool keep = (threefry_bits(idx) & 0x80000000u) == 0u;
      xs[nloc * 136 + kbase + q] = keep ? f2bf(v[q] * 2.0f) : 0;
    }
  }
  __syncthreads();
  int w = t >> 6, lane = t & 63;
  int m = lane & 15, quad = lane >> 4;
  float4v acc = {0.f, 0.f, 0.f, 0.f};
#pragma unroll
  for (int ks = 0; ks < 4; ++ks) {
    short8 a = *(const short8*)&xs[m * 136 + ks * 32 + quad * 8];
    short8 b = *(const short8*)&Ws[(w * 16 + m) * 136 + ks * 32 + quad * 8];
    acc = __builtin_amdgcn_mfma_f32_16x16x32_bf16(a, b, acc, 0, 0, 0);
  }
#pragma unroll
  for (int r = 0; r < 4; ++r) {
    int node = nodeBase + quad * 4 + r;
    y1b[node * NH + w * 16 + m] = f2bf(acc[r] * dis[node]);
  }
}

// Build the degree-sorted permutation: perm[clsbase[cls] + rank] = node.
__global__ __launch_bounds__(1024) void k_perm(const unsigned* __restrict__ rpd, const int* __restrict__ clsbase,
                                               int* __restrict__ clscur, int* __restrict__ perm, int n) {
  int i = blockIdx.x * 1024 + threadIdx.x;
  if (i < n) {
    int deg = (int)(rpd[i] & 2047u);
    int cls = deg > 63 ? 63 : deg;
    int pos = clsbase[cls] + atomicAdd(&clscur[cls], 1);
    perm[pos] = i;
  }
}

// ---------- Octet-per-node gather (degree-classed schedule) ----------
// Each 8-lane group owns ONE node (i = perm[slot], so the 8 nodes sharing a wave have
// near-equal degree -> no exec-mask divergence waste).  lane&7 picks an 8-feature slice
// (uint4 = 16B); 8 lanes x 16B = the 128B row.  8 independent chains/wave, 4-deep
// src-index prefetch, lane-local accumulate, no shfl.
#define ACC8(u) \
  a0 += __uint_as_float((u).x << 16); \
  a1 += __uint_as_float((u).x & 0xFFFF0000u); \
  a2 += __uint_as_float((u).y << 16); \
  a3 += __uint_as_float((u).y & 0xFFFF0000u); \
  a4 += __uint_as_float((u).z << 16); \
  a5 += __uint_as_float((u).z & 0xFFFF0000u); \
  a6 += __uint_as_float((u).w << 16); \
  a7 += __uint_as_float((u).w & 0xFFFF0000u);

__device__ __forceinline__ unsigned packbf(float lo, float hi) {
  return (unsigned)f2bf(lo) | ((unsigned)f2bf(hi) << 16);
}

// g = bf16( dis[i] * relu( dis[i]*(sum y1[src] + y1[i]) + b1 ) ).  Octet/node.
__global__ __launch_bounds__(256) void k_agg1(const unsigned short* __restrict__ y1b, const unsigned* __restrict__ rpd,
                                              const int* __restrict__ csrc, const float* __restrict__ dis,
                                              const float* __restrict__ b1, const int* __restrict__ perm,
                                              unsigned short* __restrict__ gb, int n) {
  int slot = blockIdx.x * 32 + (threadIdx.x >> 3);
  if (slot >= n) return;
  int i = perm[slot];
  int fl = (threadIdx.x & 7) << 3;         // feature slice start (8 bf16 = 16B)
  float di = dis[i];                       // hoisted: independent loads overlap the gather
  float4 bb0 = *(const float4*)&b1[fl];
  float4 bb1 = *(const float4*)&b1[fl + 4];
  const uint4 us = *(const uint4*)&y1b[(i << 6) + fl];   // self term
  float a0 = __uint_as_float(us.x << 16);
  float a1 = __uint_as_float(us.x & 0xFFFF0000u);
  float a2 = __uint_as_float(us.y << 16);
  float a3 = __uint_as_float(us.y & 0xFFFF0000u);
  float a4 = __uint_as_float(us.z << 16);
  float a5 = __uint_as_float(us.z & 0xFFFF0000u);
  float a6 = __uint_as_float(us.w << 16);
  float a7 = __uint_as_float(us.w & 0xFFFF0000u);
  unsigned rd = rpd[i];
  int lo = (int)(rd >> 11), hi = lo + (int)(rd & 2047u);
  int e = lo;
  int s0, s1, s2, s3;
  if (e + 4 <= hi) { s0 = csrc[e]; s1 = csrc[e + 1]; s2 = csrc[e + 2]; s3 = csrc[e + 3]; }
  for (; e + 8 <= hi; e += 4) {
    uint4 u0 = *(const uint4*)&y1b[(s0 << 6) + fl];
    uint4 u1 = *(const uint4*)&y1b[(s1 << 6) + fl];
    uint4 u2 = *(const uint4*)&y1b[(s2 << 6) + fl];
    uint4 u3 = *(const uint4*)&y1b[(s3 << 6) + fl];
    s0 = csrc[e + 4]; s1 = csrc[e + 5]; s2 = csrc[e + 6]; s3 = csrc[e + 7];
    ACC8(u0) ACC8(u1) ACC8(u2) ACC8(u3)
  }
  if (e + 4 <= hi) {
    uint4 u0 = *(const uint4*)&y1b[(s0 << 6) + fl];
    uint4 u1 = *(const uint4*)&y1b[(s1 << 6) + fl];
    uint4 u2 = *(const uint4*)&y1b[(s2 << 6) + fl];
    uint4 u3 = *(const uint4*)&y1b[(s3 << 6) + fl];
    ACC8(u0) ACC8(u1) ACC8(u2) ACC8(u3)
    e += 4;
  }
  for (; e < hi; ++e) {
    int s = csrc[e];
    uint4 u = *(const uint4*)&y1b[(s << 6) + fl];
    ACC8(u)
  }
  uint4 o;
  o.x = packbf(di * fmaxf(fmaf(di, a0, bb0.x), 0.f), di * fmaxf(fmaf(di, a1, bb0.y), 0.f));
  o.y = packbf(di * fmaxf(fmaf(di, a2, bb0.z), 0.f), di * fmaxf(fmaf(di, a3, bb0.w), 0.f));
  o.z = packbf(di * fmaxf(fmaf(di, a4, bb1.x), 0.f), di * fmaxf(fmaf(di, a5, bb1.y), 0.f));
  o.w = packbf(di * fmaxf(fmaf(di, a6, bb1.z), 0.f), di * fmaxf(fmaf(di, a7, bb1.w), 0.f));
  *(uint4*)&gb[(i << 6) + fl] = o;
}

// FUSED hop2 + output GEMM:  ah = bf16( dis[i] * (sum g[src] + g[i]) ) -> LDS,
// then out = ah @ W2 + b2 via MFMA (bit-identical to the unfused version: ah is
// bf16-rounded before the MFMA).  32 slots/block, 4 waves.
__global__ __launch_bounds__(256) void k_agg2(const unsigned short* __restrict__ gb, const unsigned* __restrict__ rpd,
                                              const int* __restrict__ csrc, const float* __restrict__ dis,
                                              const unsigned short* __restrict__ Wt2b, const float* __restrict__ b2,
                                              const int* __restrict__ perm, float* __restrict__ out, int n) {
  __shared__ unsigned short Ws[48 * 72];
  __shared__ unsigned short ahs[32 * 72];
  __shared__ int pvt[32];
  int t = threadIdx.x;
  int slotBase = blockIdx.x * 32;
  // stage W2 (bf16 padded [48][64]) into LDS; in flight during the gather phase
  for (int id = t; id < 48 * 8; id += 256) {
    int c = id >> 3, kc = id & 7;
    *(short8*)&Ws[c * 72 + kc * 8] = *(const short8*)&Wt2b[c * NH + kc * 8];
  }
  int slot = slotBase + (t >> 3);
  int fl = (t & 7) << 3;
  if (slot < n) {
    int i = perm[slot];
    if ((t & 7) == 0) pvt[t >> 3] = i;
    float di = dis[i];
    const uint4 us = *(const uint4*)&gb[(i << 6) + fl];
    float a0 = __uint_as_float(us.x << 16);
    float a1 = __uint_as_float(us.x & 0xFFFF0000u);
    float a2 = __uint_as_float(us.y << 16);
    float a3 = __uint_as_float(us.y & 0xFFFF0000u);
    float a4 = __uint_as_float(us.z << 16);
    float a5 = __uint_as_float(us.z & 0xFFFF0000u);
    float a6 = __uint_as_float(us.w << 16);
    float a7 = __uint_as_float(us.w & 0xFFFF0000u);
    unsigned rd = rpd[i];
    int lo = (int)(rd >> 11), hi = lo + (int)(rd & 2047u);
    int e = lo;
    int s0, s1, s2, s3;
    if (e + 4 <= hi) { s0 = csrc[e]; s1 = csrc[e + 1]; s2 = csrc[e + 2]; s3 = csrc[e + 3]; }
    for (; e + 8 <= hi; e += 4) {
      uint4 u0 = *(const uint4*)&gb[(s0 << 6) + fl];
      uint4 u1 = *(const uint4*)&gb[(s1 << 6) + fl];
      uint4 u2 = *(const uint4*)&gb[(s2 << 6) + fl];
      uint4 u3 = *(const uint4*)&gb[(s3 << 6) + fl];
      s0 = csrc[e + 4]; s1 = csrc[e + 5]; s2 = csrc[e + 6]; s3 = csrc[e + 7];
      ACC8(u0) ACC8(u1) ACC8(u2) ACC8(u3)
    }
    if (e + 4 <= hi) {
      uint4 u0 = *(const uint4*)&gb[(s0 << 6) + fl];
      uint4 u1 = *(const uint4*)&gb[(s1 << 6) + fl];
      uint4 u2 = *(const uint4*)&gb[(s2 << 6) + fl];
      uint4 u3 = *(const uint4*)&gb[(s3 << 6) + fl];
      ACC8(u0) ACC8(u1) ACC8(u2) ACC8(u3)
      e += 4;
    }
    for (; e < hi; ++e) {
      int s = csrc[e];
      uint4 u = *(const uint4*)&gb[(s << 6) + fl];
      ACC8(u)
    }
    uint4 o;
    o.x = packbf(di * a0, di * a1);
    o.y = packbf(di * a2, di * a3);
    o.z = packbf(di * a4, di * a5);
    o.w = packbf(di * a6, di * a7);
    *(uint4*)&ahs[(t >> 3) * 72 + fl] = o;
  }
  __syncthreads();
  int w = t >> 6, lane = t & 63;
  int m = lane & 15, quad = lane >> 4;
  if (w < 3) {                              // 3 waves cover 48 padded cols
#pragma unroll
    for (int mt = 0; mt < 2; ++mt) {        // 2 m-tiles of 16 slots
      float4v acc = {0.f, 0.f, 0.f, 0.f};
#pragma unroll
      for (int ks = 0; ks < 2; ++ks) {
        short8 a = *(const short8*)&ahs[(mt * 16 + m) * 72 + ks * 32 + quad * 8];
        short8 b = *(const short8*)&Ws[(w * 16 + m) * 72 + ks * 32 + quad * 8];
        acc = __builtin_amdgcn_mfma_f32_16x16x32_bf16(a, b, acc, 0, 0, 0);
      }
      int col = w * 16 + m;
      if (col < NC) {
        float bias = b2[col];
#pragma unroll
        for (int r = 0; r < 4; ++r) {
          int sl = mt * 16 + quad * 4 + r;
          if (slotBase + sl < n) {
            int node = pvt[sl];
            out[node * NC + col] = acc[r] + bias;
          }
        }
      }
    }
  }
}

extern "C" void kernel_launch(void* const* d_in, const int* in_sizes, int n_in,
                              void* d_out, int out_size, void* d_ws, size_t ws_size,
                              hipStream_t stream) {
  const float* x  = (const float*)d_in[0];
  const int*   ei = (const int*)d_in[1];
  const float* W1 = (const float*)d_in[2];
  const float* b1 = (const float*)d_in[3];
  const float* W2 = (const float*)d_in[4];
  const float* b2 = (const float*)d_in[5];
  float* out = (float*)d_out;
  int n  = in_sizes[0] / NF;    // 100000
  int nE = in_sizes[1] / 2;     // 1600000
  const int* src = ei;
  const int* dst = ei + nE;

  char* ws = (char*)d_ws;
  float*    dis    = (float*)(ws + 0);                 // 400 KB
  unsigned* rpd    = (unsigned*)(ws + 400000);         // 400 KB (start<<11 | deg)
  int*      gcur   = (int*)(ws + 800000);              // 98 ints (one memset covers gcur..clscur)
  int*      clscnt = (int*)(ws + 800392);              // 64 ints
  int*      clscur = (int*)(ws + 800648);              // 64 ints
  int*      clsbase= (int*)(ws + 800904);              // 64 ints (written by k_xw blk0)
  unsigned short* Wt1b = (unsigned short*)(ws + 801280);   // 16 KB
  unsigned short* Wt2b = (unsigned short*)(ws + 817664);   // 6 KB
  int*      perm   = (int*)(ws + 823808);              // 400 KB
  int*      csrc   = (int*)(ws + 1223808);             // 98*20480*4 = 8,028,160 B
  unsigned short* y1b = (unsigned short*)(ws + 9251968);   // 12.8 MB
  unsigned short* gb  = (unsigned short*)(ws + 22051968);  // 12.8 MB
  unsigned* binned = (unsigned*)(ws + 22051968);       // 8.03 MB, overlays gb (dead before agg1)

  (void)hipMemsetAsync(gcur, 0, (NB + 128) * 4, stream);   // gcur + clscnt + clscur

  int nbin = (nE + BIN_T - 1) / BIN_T;                 // 782
  int nprep = (NF * NH + 48 * NH + 255) / 256;         // 44
  k_bin  <<<nbin + nprep, 256, 0, stream>>>(src, dst, gcur, binned, W1, W2, Wt1b, Wt2b, nE, nbin);
  k_fillb<<<NB, 1024, 0, stream>>>(binned, gcur, rpd, dis, csrc, clscnt, n);
  k_xw   <<<n / 16, 256, 0, stream>>>(x, Wt1b, dis, y1b, clscnt, clsbase, n);
  k_perm <<<(n + 1023) / 1024, 1024, 0, stream>>>(rpd, clsbase, clscur, perm, n);
  k_agg1 <<<(n + 31) / 32, 256, 0, stream>>>(y1b, rpd, csrc, dis, b1, perm, gb, n);
  k_agg2 <<<(n + 31) / 32, 256, 0, stream>>>(gb, rpd, csrc, dis, Wt2b, b2, perm, out, n);
}

// Round 9
// 228.380 us; speedup vs baseline: 2.2764x; 2.2764x over previous
//
#include <hip/hip_runtime.h>

#define NF 128
#define NH 64
#define NC 40
#define BSHIFT 10                 // bucket = dst >> 10  (1024 nodes/bucket)
#define NB 98                     // ceil(100000 / 1024)
#define BIN_T 2048                // edges per k_bin block
#define BSTRIDE 20480             // fixed slots per bucket (mean 16327, sigma 128 -> 32-sigma safe)

typedef __attribute__((ext_vector_type(8))) short short8;
typedef __attribute__((ext_vector_type(4))) float float4v;

__device__ __forceinline__ unsigned rotl32(unsigned v, int s) { return (v << s) | (v >> (32 - s)); }

__device__ __forceinline__ unsigned short f2bf(float f) {   // fp32 -> bf16 RNE
  unsigned u = __float_as_uint(f);
  return (unsigned short)((u + 0x7FFFu + ((u >> 16) & 1u)) >> 16);
}
__device__ __forceinline__ float bf2f(unsigned short b) {
  return __uint_as_float(((unsigned)b) << 16);
}

// threefry2x32, key(0,42), partitionable path: bits = x0^x1 of counter (0, idx).
__device__ __forceinline__ unsigned threefry_bits(unsigned idx) {
  const unsigned k0 = 0u, k1 = 42u;
  const unsigned k2x = 0u ^ 42u ^ 0x1BD11BDAu;
  unsigned x0 = 0u, x1 = idx;
  x0 += k0; x1 += k1;
  x0 += x1; x1 = rotl32(x1, 13); x1 ^= x0;
  x0 += x1; x1 = rotl32(x1, 15); x1 ^= x0;
  x0 += x1; x1 = rotl32(x1, 26); x1 ^= x0;
  x0 += x1; x1 = rotl32(x1, 6);  x1 ^= x0;
  x0 += k1; x1 += k2x + 1u;
  x0 += x1; x1 = rotl32(x1, 17); x1 ^= x0;
  x0 += x1; x1 = rotl32(x1, 29); x1 ^= x0;
  x0 += x1; x1 = rotl32(x1, 16); x1 ^= x0;
  x0 += x1; x1 = rotl32(x1, 24); x1 ^= x0;
  x0 += k2x; x1 += k0 + 2u;
  x0 += x1; x1 = rotl32(x1, 13); x1 ^= x0;
  x0 += x1; x1 = rotl32(x1, 15); x1 ^= x0;
  x0 += x1; x1 = rotl32(x1, 26); x1 ^= x0;
  x0 += x1; x1 = rotl32(x1, 6);  x1 ^= x0;
  x0 += k0; x1 += k1 + 3u;
  x0 += x1; x1 = rotl32(x1, 17); x1 ^= x0;
  x0 += x1; x1 = rotl32(x1, 29); x1 ^= x0;
  x0 += x1; x1 = rotl32(x1, 16); x1 ^= x0;
  x0 += x1; x1 = rotl32(x1, 24); x1 ^= x0;
  x0 += k1; x1 += k2x + 4u;
  x0 += x1; x1 = rotl32(x1, 13); x1 ^= x0;
  x0 += x1; x1 = rotl32(x1, 15); x1 ^= x0;
  x0 += x1; x1 = rotl32(x1, 26); x1 ^= x0;
  x0 += x1; x1 = rotl32(x1, 6);  x1 ^= x0;
  x0 += k2x; x1 += k0 + 5u;
  return x0 ^ x1;
}

// Bin edges into fixed-stride buckets; packed word = (src<<10) | (dst & 1023).
// Blocks >= nbin do the one-shot weight prep (W1 -> bf16 [c][k]; W2 -> bf16 padded [c<48][k<64]).
__global__ __launch_bounds__(256) void k_bin(const int* __restrict__ src, const int* __restrict__ dst,
                                             int* __restrict__ gcur, unsigned* __restrict__ binned,
                                             const float* __restrict__ W1, const float* __restrict__ W2,
                                             unsigned short* __restrict__ Wt1b, unsigned short* __restrict__ Wt2b,
                                             int nE, int nbin) {
  int t = threadIdx.x;
  if (blockIdx.x >= nbin) {                 // weight-prep blocks
    int id = (blockIdx.x - nbin) * 256 + t;
    if (id < NF * NH) {
      int k = id >> 6, c = id & 63;
      Wt1b[c * NF + k] = f2bf(W1[id]);
    } else if (id < NF * NH + 48 * NH) {
      int id2 = id - NF * NH;
      int c = id2 >> 6, k = id2 & 63;
      Wt2b[c * NH + k] = (c < NC) ? f2bf(W2[k * NC + c]) : 0;
    }
    return;
  }
  __shared__ int h[NB];
  __shared__ int off[NB];
  int b0 = blockIdx.x * BIN_T;
  int b1 = b0 + BIN_T; if (b1 > nE) b1 = nE;
  if (t < NB) h[t] = 0;
  __syncthreads();
  for (int e = b0 + t; e < b1; e += 256)
    atomicAdd(&h[dst[e] >> BSHIFT], 1);
  __syncthreads();
  if (t < NB && h[t] > 0) off[t] = t * BSTRIDE + atomicAdd(&gcur[t], h[t]);
  __syncthreads();
  for (int e = b0 + t; e < b1; e += 256) {
    int s = src[e], d = dst[e];
    int p = atomicAdd(&off[d >> BSHIFT], 1);
    binned[p] = ((unsigned)s << BSHIFT) | (unsigned)(d & ((1 << BSHIFT) - 1));
  }
}

// Per-bucket: node degree hist -> shfl-scan -> rpd (packed start<<11|deg) + dis, then place csrc.
__global__ __launch_bounds__(1024) void k_fillb(const unsigned* __restrict__ binned, const int* __restrict__ gcur,
                                                unsigned* __restrict__ rpd, float* __restrict__ dis,
                                                int* __restrict__ csrc, int n) {
  __shared__ int hist[1024];
  __shared__ int wsum[16];
  int b = blockIdx.x;
  int base = b << BSHIFT;
  int t = threadIdx.x;
  int lo = b * BSTRIDE, hi = lo + gcur[b];
  hist[t] = 0;
  __syncthreads();
  for (int e = lo + t; e < hi; e += 1024)
    atomicAdd(&hist[binned[e] & 1023u], 1);
  __syncthreads();
  int v = hist[t];
  // wave-level inclusive scan (64 lanes, no barriers)
  int sv = v;
#pragma unroll
  for (int off = 1; off < 64; off <<= 1) {
    int u = __shfl_up(sv, off);
    if ((t & 63) >= off) sv += u;
  }
  int wid = t >> 6;
  if ((t & 63) == 63) wsum[wid] = sv;
  __syncthreads();
  if (t < 16) {                       // scan the 16 wave totals -> exclusive
    int ws = wsum[t];
    int sws = ws;
#pragma unroll
    for (int off = 1; off < 16; off <<= 1) {
      int u = __shfl_up(sws, off);
      if (t >= off) sws += u;
    }
    wsum[t] = sws - ws;
  }
  __syncthreads();
  int excl = sv - v + wsum[wid];
  if (base + t < n) {
    rpd[base + t] = ((unsigned)(lo + excl) << 11) | (unsigned)v;
    dis[base + t] = rsqrtf((float)(v + 1));
  }
  __syncthreads();
  hist[t] = lo + excl;
  __syncthreads();
  for (int e = lo + t; e < hi; e += 1024) {
    unsigned p = binned[e];
    int pos = atomicAdd(&hist[p & 1023u], 1);
    csrc[pos] = (int)(p >> BSHIFT);
  }
}

// y1 = bf16( dis[i] * (dropout(x) @ W1) ) via MFMA bf16.  16 nodes/block, 4 waves.
__global__ __launch_bounds__(256) void k_xw(const float* __restrict__ x, const unsigned short* __restrict__ Wt1b,
                                            const float* __restrict__ dis, unsigned short* __restrict__ y1b, int n) {
  __shared__ unsigned short Ws[NH * 136];
  __shared__ unsigned short xs[16 * 136];
  int t = threadIdx.x;
  int nodeBase = blockIdx.x * 16;
  for (int id = t; id < NH * 16; id += 256) {
    int c = id >> 4, kc = id & 15;
    *(short8*)&Ws[c * 136 + kc * 8] = *(const short8*)&Wt1b[c * NF + kc * 8];
  }
  {
    int nloc = t >> 4, kbase = (t & 15) * 8;
    int ebase = (nodeBase + nloc) * NF + kbase;
    const float4* xp = (const float4*)x;
    float4 a = xp[(ebase >> 2)];
    float4 b = xp[(ebase >> 2) + 1];
    float v[8] = {a.x, a.y, a.z, a.w, b.x, b.y, b.z, b.w};
#pragma unroll
    for (int q = 0; q < 8; ++q) {
      unsigned idx = (unsigned)(ebase + q);
      bool keep = (threefry_bits(idx) & 0x80000000u) == 0u;
      xs[nloc * 136 + kbase + q] = keep ? f2bf(v[q] * 2.0f) : 0;
    }
  }
  __syncthreads();
  int w = t >> 6, lane = t & 63;
  int m = lane & 15, quad = lane >> 4;
  float4v acc = {0.f, 0.f, 0.f, 0.f};
#pragma unroll
  for (int ks = 0; ks < 4; ++ks) {
    short8 a = *(const short8*)&xs[m * 136 + ks * 32 + quad * 8];
    short8 b = *(const short8*)&Ws[(w * 16 + m) * 136 + ks * 32 + quad * 8];
    acc = __builtin_amdgcn_mfma_f32_16x16x32_bf16(a, b, acc, 0, 0, 0);
  }
#pragma unroll
  for (int r = 0; r < 4; ++r) {
    int node = nodeBase + quad * 4 + r;
    y1b[node * NH + w * 16 + m] = f2bf(acc[r] * dis[node]);
  }
}

// ---------- Octet-per-node gather ----------
// Each 8-lane group owns ONE node: lane&7 selects an 8-feature slice (uint4 = 16B),
// 8 lanes x 16B = the full 128B feature row. A wave carries 8 independent nodes ->
// 8 independent load-dependency chains, one wave-load instruction covers 8 edges.
// 4-deep src-index prefetch per chain.  No shfl; lane-local accumulate.
#define ACC8(u) \
  a0 += __uint_as_float((u).x << 16); \
  a1 += __uint_as_float((u).x & 0xFFFF0000u); \
  a2 += __uint_as_float((u).y << 16); \
  a3 += __uint_as_float((u).y & 0xFFFF0000u); \
  a4 += __uint_as_float((u).z << 16); \
  a5 += __uint_as_float((u).z & 0xFFFF0000u); \
  a6 += __uint_as_float((u).w << 16); \
  a7 += __uint_as_float((u).w & 0xFFFF0000u);

__device__ __forceinline__ unsigned packbf(float lo, float hi) {
  return (unsigned)f2bf(lo) | ((unsigned)f2bf(hi) << 16);
}

// g = bf16( dis[i] * relu( dis[i]*(sum y1[src] + y1[i]) + b1 ) ).  Octet/node.
__global__ __launch_bounds__(256) void k_agg1(const unsigned short* __restrict__ y1b, const unsigned* __restrict__ rpd,
                                              const int* __restrict__ csrc, const float* __restrict__ dis,
                                              const float* __restrict__ b1, unsigned short* __restrict__ gb, int n) {
  int i = blockIdx.x * 32 + (threadIdx.x >> 3);
  if (i >= n) return;
  int fl = (threadIdx.x & 7) << 3;         // feature slice start (8 bf16 = 16B)
  float di = dis[i];                       // hoisted: independent loads overlap the gather
  float4 bb0 = *(const float4*)&b1[fl];
  float4 bb1 = *(const float4*)&b1[fl + 4];
  const uint4 us = *(const uint4*)&y1b[(i << 6) + fl];   // self term
  float a0 = __uint_as_float(us.x << 16);
  float a1 = __uint_as_float(us.x & 0xFFFF0000u);
  float a2 = __uint_as_float(us.y << 16);
  float a3 = __uint_as_float(us.y & 0xFFFF0000u);
  float a4 = __uint_as_float(us.z << 16);
  float a5 = __uint_as_float(us.z & 0xFFFF0000u);
  float a6 = __uint_as_float(us.w << 16);
  float a7 = __uint_as_float(us.w & 0xFFFF0000u);
  unsigned rd = rpd[i];
  int lo = (int)(rd >> 11), hi = lo + (int)(rd & 2047u);
  int e = lo;
  int s0, s1, s2, s3;
  if (e + 4 <= hi) { s0 = csrc[e]; s1 = csrc[e + 1]; s2 = csrc[e + 2]; s3 = csrc[e + 3]; }
  for (; e + 8 <= hi; e += 4) {
    uint4 u0 = *(const uint4*)&y1b[(s0 << 6) + fl];
    uint4 u1 = *(const uint4*)&y1b[(s1 << 6) + fl];
    uint4 u2 = *(const uint4*)&y1b[(s2 << 6) + fl];
    uint4 u3 = *(const uint4*)&y1b[(s3 << 6) + fl];
    s0 = csrc[e + 4]; s1 = csrc[e + 5]; s2 = csrc[e + 6]; s3 = csrc[e + 7];
    ACC8(u0) ACC8(u1) ACC8(u2) ACC8(u3)
  }
  if (e + 4 <= hi) {
    uint4 u0 = *(const uint4*)&y1b[(s0 << 6) + fl];
    uint4 u1 = *(const uint4*)&y1b[(s1 << 6) + fl];
    uint4 u2 = *(const uint4*)&y1b[(s2 << 6) + fl];
    uint4 u3 = *(const uint4*)&y1b[(s3 << 6) + fl];
    ACC8(u0) ACC8(u1) ACC8(u2) ACC8(u3)
    e += 4;
  }
  for (; e < hi; ++e) {
    int s = csrc[e];
    uint4 u = *(const uint4*)&y1b[(s << 6) + fl];
    ACC8(u)
  }
  uint4 o;
  o.x = packbf(di * fmaxf(fmaf(di, a0, bb0.x), 0.f), di * fmaxf(fmaf(di, a1, bb0.y), 0.f));
  o.y = packbf(di * fmaxf(fmaf(di, a2, bb0.z), 0.f), di * fmaxf(fmaf(di, a3, bb0.w), 0.f));
  o.z = packbf(di * fmaxf(fmaf(di, a4, bb1.x), 0.f), di * fmaxf(fmaf(di, a5, bb1.y), 0.f));
  o.w = packbf(di * fmaxf(fmaf(di, a6, bb1.z), 0.f), di * fmaxf(fmaf(di, a7, bb1.w), 0.f));
  *(uint4*)&gb[(i << 6) + fl] = o;
}

// FUSED hop2 + output GEMM:  ah = bf16( dis[i] * (sum g[src] + g[i]) ) -> LDS,
// then out = ah @ W2 + b2 via MFMA (bit-identical to the unfused version: ah is
// bf16-rounded before the MFMA).  32 nodes/block, 4 waves.
__global__ __launch_bounds__(256) void k_agg2(const unsigned short* __restrict__ gb, const unsigned* __restrict__ rpd,
                                              const int* __restrict__ csrc, const float* __restrict__ dis,
                                              const unsigned short* __restrict__ Wt2b, const float* __restrict__ b2,
                                              float* __restrict__ out, int n) {
  __shared__ unsigned short Ws[48 * 72];
  __shared__ unsigned short ahs[32 * 72];
  int t = threadIdx.x;
  int nodeBase = blockIdx.x * 32;
  // stage W2 (bf16 padded [48][64]) into LDS; in flight during the gather phase
  for (int id = t; id < 48 * 8; id += 256) {
    int c = id >> 3, kc = id & 7;
    *(short8*)&Ws[c * 72 + kc * 8] = *(const short8*)&Wt2b[c * NH + kc * 8];
  }
  int i = nodeBase + (t >> 3);
  int fl = (t & 7) << 3;
  if (i < n) {
    float di = dis[i];
    const uint4 us = *(const uint4*)&gb[(i << 6) + fl];
    float a0 = __uint_as_float(us.x << 16);
    float a1 = __uint_as_float(us.x & 0xFFFF0000u);
    float a2 = __uint_as_float(us.y << 16);
    float a3 = __uint_as_float(us.y & 0xFFFF0000u);
    float a4 = __uint_as_float(us.z << 16);
    float a5 = __uint_as_float(us.z & 0xFFFF0000u);
    float a6 = __uint_as_float(us.w << 16);
    float a7 = __uint_as_float(us.w & 0xFFFF0000u);
    unsigned rd = rpd[i];
    int lo = (int)(rd >> 11), hi = lo + (int)(rd & 2047u);
    int e = lo;
    int s0, s1, s2, s3;
    if (e + 4 <= hi) { s0 = csrc[e]; s1 = csrc[e + 1]; s2 = csrc[e + 2]; s3 = csrc[e + 3]; }
    for (; e + 8 <= hi; e += 4) {
      uint4 u0 = *(const uint4*)&gb[(s0 << 6) + fl];
      uint4 u1 = *(const uint4*)&gb[(s1 << 6) + fl];
      uint4 u2 = *(const uint4*)&gb[(s2 << 6) + fl];
      uint4 u3 = *(const uint4*)&gb[(s3 << 6) + fl];
      s0 = csrc[e + 4]; s1 = csrc[e + 5]; s2 = csrc[e + 6]; s3 = csrc[e + 7];
      ACC8(u0) ACC8(u1) ACC8(u2) ACC8(u3)
    }
    if (e + 4 <= hi) {
      uint4 u0 = *(const uint4*)&gb[(s0 << 6) + fl];
      uint4 u1 = *(const uint4*)&gb[(s1 << 6) + fl];
      uint4 u2 = *(const uint4*)&gb[(s2 << 6) + fl];
      uint4 u3 = *(const uint4*)&gb[(s3 << 6) + fl];
      ACC8(u0) ACC8(u1) ACC8(u2) ACC8(u3)
      e += 4;
    }
    for (; e < hi; ++e) {
      int s = csrc[e];
      uint4 u = *(const uint4*)&gb[(s << 6) + fl];
      ACC8(u)
    }
    uint4 o;
    o.x = packbf(di * a0, di * a1);
    o.y = packbf(di * a2, di * a3);
    o.z = packbf(di * a4, di * a5);
    o.w = packbf(di * a6, di * a7);
    *(uint4*)&ahs[(t >> 3) * 72 + fl] = o;
  }
  __syncthreads();
  int w = t >> 6, lane = t & 63;
  int m = lane & 15, quad = lane >> 4;
  if (w < 3) {                              // 3 waves cover 48 padded cols
#pragma unroll
    for (int mt = 0; mt < 2; ++mt) {        // 2 m-tiles of 16 nodes
      float4v acc = {0.f, 0.f, 0.f, 0.f};
#pragma unroll
      for (int ks = 0; ks < 2; ++ks) {
        short8 a = *(const short8*)&ahs[(mt * 16 + m) * 72 + ks * 32 + quad * 8];
        short8 b = *(const short8*)&Ws[(w * 16 + m) * 72 + ks * 32 + quad * 8];
        acc = __builtin_amdgcn_mfma_f32_16x16x32_bf16(a, b, acc, 0, 0, 0);
      }
      int col = w * 16 + m;
      if (col < NC) {
        float bias = b2[col];
#pragma unroll
        for (int r = 0; r < 4; ++r) {
          int node = nodeBase + mt * 16 + quad * 4 + r;
          if (node < n) out[node * NC + col] = acc[r] + bias;
        }
      }
    }
  }
}

extern "C" void kernel_launch(void* const* d_in, const int* in_sizes, int n_in,
                              void* d_out, int out_size, void* d_ws, size_t ws_size,
                              hipStream_t stream) {
  const float* x  = (const float*)d_in[0];
  const int*   ei = (const int*)d_in[1];
  const float* W1 = (const float*)d_in[2];
  const float* b1 = (const float*)d_in[3];
  const float* W2 = (const float*)d_in[4];
  const float* b2 = (const float*)d_in[5];
  float* out = (float*)d_out;
  int n  = in_sizes[0] / NF;    // 100000
  int nE = in_sizes[1] / 2;     // 1600000
  const int* src = ei;
  const int* dst = ei + nE;

  char* ws = (char*)d_ws;
  float*    dis  = (float*)(ws + 0);                   // 400 KB
  unsigned* rpd  = (unsigned*)(ws + 400000);           // 400 KB (start<<11 | deg)
  int*      gcur = (int*)(ws + 800000);                // 98 ints
  unsigned short* Wt1b = (unsigned short*)(ws + 800512);   // 16 KB
  unsigned short* Wt2b = (unsigned short*)(ws + 816896);   // 6 KB
  int*      csrc = (int*)(ws + 823296);                // 98*20480*4 = 8,028,160 B
  unsigned short* y1b = (unsigned short*)(ws + 8851456);   // 12.8 MB
  unsigned short* gb  = (unsigned short*)(ws + 21651456);  // 12.8 MB
  unsigned* binned = (unsigned*)(ws + 21651456);       // 8.03 MB, overlays gb (dead before agg1)

  (void)hipMemsetAsync(gcur, 0, NB * 4, stream);

  int nbin = (nE + BIN_T - 1) / BIN_T;                 // 782
  int nprep = (NF * NH + 48 * NH + 255) / 256;         // 44
  k_bin  <<<nbin + nprep, 256, 0, stream>>>(src, dst, gcur, binned, W1, W2, Wt1b, Wt2b, nE, nbin);
  k_fillb<<<NB, 1024, 0, stream>>>(binned, gcur, rpd, dis, csrc, n);
  k_xw   <<<n / 16, 256, 0, stream>>>(x, Wt1b, dis, y1b, n);
  k_agg1 <<<(n + 31) / 32, 256, 0, stream>>>(y1b, rpd, csrc, dis, b1, gb, n);
  k_agg2 <<<(n + 31) / 32, 256, 0, stream>>>(gb, rpd, csrc, dis, Wt2b, b2, out, n);
}

// Round 10
// 222.145 us; speedup vs baseline: 2.3403x; 1.0281x over previous
//
#include <hip/hip_runtime.h>

#define NF 128
#define NH 64
#define NC 40
#define BSHIFT 10                 // bucket = dst >> 10  (1024 nodes/bucket)
#define NB 98                     // ceil(100000 / 1024)
#define BIN_T 8192                // edges per k_bin block (measured optimum, R6)
#define BSTRIDE 20480             // fixed slots per bucket (mean 16327, sigma 128 -> 32-sigma safe)

typedef __attribute__((ext_vector_type(8))) short short8;
typedef __attribute__((ext_vector_type(4))) float float4v;

__device__ __forceinline__ unsigned rotl32(unsigned v, int s) { return (v << s) | (v >> (32 - s)); }

__device__ __forceinline__ unsigned short f2bf(float f) {   // fp32 -> bf16 RNE
  unsigned u = __float_as_uint(f);
  return (unsigned short)((u + 0x7FFFu + ((u >> 16) & 1u)) >> 16);
}
__device__ __forceinline__ float bf2f(unsigned short b) {
  return __uint_as_float(((unsigned)b) << 16);
}

// threefry2x32, key(0,42), partitionable path: bits = x0^x1 of counter (0, idx).
__device__ __forceinline__ unsigned threefry_bits(unsigned idx) {
  const unsigned k0 = 0u, k1 = 42u;
  const unsigned k2x = 0u ^ 42u ^ 0x1BD11BDAu;
  unsigned x0 = 0u, x1 = idx;
  x0 += k0; x1 += k1;
  x0 += x1; x1 = rotl32(x1, 13); x1 ^= x0;
  x0 += x1; x1 = rotl32(x1, 15); x1 ^= x0;
  x0 += x1; x1 = rotl32(x1, 26); x1 ^= x0;
  x0 += x1; x1 = rotl32(x1, 6);  x1 ^= x0;
  x0 += k1; x1 += k2x + 1u;
  x0 += x1; x1 = rotl32(x1, 17); x1 ^= x0;
  x0 += x1; x1 = rotl32(x1, 29); x1 ^= x0;
  x0 += x1; x1 = rotl32(x1, 16); x1 ^= x0;
  x0 += x1; x1 = rotl32(x1, 24); x1 ^= x0;
  x0 += k2x; x1 += k0 + 2u;
  x0 += x1; x1 = rotl32(x1, 13); x1 ^= x0;
  x0 += x1; x1 = rotl32(x1, 15); x1 ^= x0;
  x0 += x1; x1 = rotl32(x1, 26); x1 ^= x0;
  x0 += x1; x1 = rotl32(x1, 6);  x1 ^= x0;
  x0 += k0; x1 += k1 + 3u;
  x0 += x1; x1 = rotl32(x1, 17); x1 ^= x0;
  x0 += x1; x1 = rotl32(x1, 29); x1 ^= x0;
  x0 += x1; x1 = rotl32(x1, 16); x1 ^= x0;
  x0 += x1; x1 = rotl32(x1, 24); x1 ^= x0;
  x0 += k1; x1 += k2x + 4u;
  x0 += x1; x1 = rotl32(x1, 13); x1 ^= x0;
  x0 += x1; x1 = rotl32(x1, 15); x1 ^= x0;
  x0 += x1; x1 = rotl32(x1, 26); x1 ^= x0;
  x0 += x1; x1 = rotl32(x1, 6);  x1 ^= x0;
  x0 += k2x; x1 += k0 + 5u;
  return x0 ^ x1;
}

// Bin edges into fixed-stride buckets; packed word = (src<<10) | (dst & 1023).
// Blocks >= nbin do the one-shot weight prep (W1 -> bf16 [c][k]; W2 -> bf16 padded [c<48][k<64]).
__global__ __launch_bounds__(256) void k_bin(const int* __restrict__ src, const int* __restrict__ dst,
                                             int* __restrict__ gcur, unsigned* __restrict__ binned,
                                             const float* __restrict__ W1, const float* __restrict__ W2,
                                             unsigned short* __restrict__ Wt1b, unsigned short* __restrict__ Wt2b,
                                             int nE, int nbin) {
  int t = threadIdx.x;
  if (blockIdx.x >= nbin) {                 // weight-prep blocks
    int id = (blockIdx.x - nbin) * 256 + t;
    if (id < NF * NH) {
      int k = id >> 6, c = id & 63;
      Wt1b[c * NF + k] = f2bf(W1[id]);
    } else if (id < NF * NH + 48 * NH) {
      int id2 = id - NF * NH;
      int c = id2 >> 6, k = id2 & 63;
      Wt2b[c * NH + k] = (c < NC) ? f2bf(W2[k * NC + c]) : 0;
    }
    return;
  }
  __shared__ int h[NB];
  __shared__ int off[NB];
  int b0 = blockIdx.x * BIN_T;
  int b1 = b0 + BIN_T; if (b1 > nE) b1 = nE;
  if (t < NB) h[t] = 0;
  __syncthreads();
  for (int e = b0 + t; e < b1; e += 256)
    atomicAdd(&h[dst[e] >> BSHIFT], 1);
  __syncthreads();
  if (t < NB && h[t] > 0) off[t] = t * BSTRIDE + atomicAdd(&gcur[t], h[t]);
  __syncthreads();
  for (int e = b0 + t; e < b1; e += 256) {
    int s = src[e], d = dst[e];
    int p = atomicAdd(&off[d >> BSHIFT], 1);
    binned[p] = ((unsigned)s << BSHIFT) | (unsigned)(d & ((1 << BSHIFT) - 1));
  }
}

// Per-bucket: node degree hist -> shfl-scan -> rpd (packed start<<11|deg) + dis, then place csrc.
__global__ __launch_bounds__(1024) void k_fillb(const unsigned* __restrict__ binned, const int* __restrict__ gcur,
                                                unsigned* __restrict__ rpd, float* __restrict__ dis,
                                                int* __restrict__ csrc, int n) {
  __shared__ int hist[1024];
  __shared__ int wsum[16];
  int b = blockIdx.x;
  int base = b << BSHIFT;
  int t = threadIdx.x;
  int lo = b * BSTRIDE, hi = lo + gcur[b];
  hist[t] = 0;
  __syncthreads();
  for (int e = lo + t; e < hi; e += 1024)
    atomicAdd(&hist[binned[e] & 1023u], 1);
  __syncthreads();
  int v = hist[t];
  // wave-level inclusive scan (64 lanes, no barriers)
  int sv = v;
#pragma unroll
  for (int off = 1; off < 64; off <<= 1) {
    int u = __shfl_up(sv, off);
    if ((t & 63) >= off) sv += u;
  }
  int wid = t >> 6;
  if ((t & 63) == 63) wsum[wid] = sv;
  __syncthreads();
  if (t < 16) {                       // scan the 16 wave totals -> exclusive
    int ws = wsum[t];
    int sws = ws;
#pragma unroll
    for (int off = 1; off < 16; off <<= 1) {
      int u = __shfl_up(sws, off);
      if (t >= off) sws += u;
    }
    wsum[t] = sws - ws;
  }
  __syncthreads();
  int excl = sv - v + wsum[wid];
  if (base + t < n) {
    rpd[base + t] = ((unsigned)(lo + excl) << 11) | (unsigned)v;
    dis[base + t] = rsqrtf((float)(v + 1));
  }
  __syncthreads();
  hist[t] = lo + excl;
  __syncthreads();
  for (int e = lo + t; e < hi; e += 1024) {
    unsigned p = binned[e];
    int pos = atomicAdd(&hist[p & 1023u], 1);
    csrc[pos] = (int)(p >> BSHIFT);
  }
}

// y1 = bf16( dis[i] * (dropout(x) @ W1) ) via MFMA bf16.  16 nodes/block, 4 waves.
__global__ __launch_bounds__(256) void k_xw(const float* __restrict__ x, const unsigned short* __restrict__ Wt1b,
                                            const float* __restrict__ dis, unsigned short* __restrict__ y1b, int n) {
  __shared__ unsigned short Ws[NH * 136];
  __shared__ unsigned short xs[16 * 136];
  int t = threadIdx.x;
  int nodeBase = blockIdx.x * 16;
  for (int id = t; id < NH * 16; id += 256) {
    int c = id >> 4, kc = id & 15;
    *(short8*)&Ws[c * 136 + kc * 8] = *(const short8*)&Wt1b[c * NF + kc * 8];
  }
  {
    int nloc = t >> 4, kbase = (t & 15) * 8;
    int ebase = (nodeBase + nloc) * NF + kbase;
    const float4* xp = (const float4*)x;
    float4 a = xp[(ebase >> 2)];
    float4 b = xp[(ebase >> 2) + 1];
    float v[8] = {a.x, a.y, a.z, a.w, b.x, b.y, b.z, b.w};
#pragma unroll
    for (int q = 0; q < 8; ++q) {
      unsigned idx = (unsigned)(ebase + q);
      bool keep = (threefry_bits(idx) & 0x80000000u) == 0u;
      xs[nloc * 136 + kbase + q] = keep ? f2bf(v[q] * 2.0f) : 0;
    }
  }
  __syncthreads();
  int w = t >> 6, lane = t & 63;
  int m = lane & 15, quad = lane >> 4;
  float4v acc = {0.f, 0.f, 0.f, 0.f};
#pragma unroll
  for (int ks = 0; ks < 4; ++ks) {
    short8 a = *(const short8*)&xs[m * 136 + ks * 32 + quad * 8];
    short8 b = *(const short8*)&Ws[(w * 16 + m) * 136 + ks * 32 + quad * 8];
    acc = __builtin_amdgcn_mfma_f32_16x16x32_bf16(a, b, acc, 0, 0, 0);
  }
#pragma unroll
  for (int r = 0; r < 4; ++r) {
    int node = nodeBase + quad * 4 + r;
    y1b[node * NH + w * 16 + m] = f2bf(acc[r] * dis[node]);
  }
}

// ---------- Octet-per-node gather ----------
// Each 8-lane group owns ONE node: lane&7 selects an 8-feature slice (uint4 = 16B),
// 8 lanes x 16B = the full 128B feature row. A wave carries 8 independent nodes ->
// 8 independent load-dependency chains, one wave-load instruction covers 8 edges.
// 4-deep src-index prefetch per chain.  No shfl; lane-local accumulate.
#define ACC8(u) \
  a0 += __uint_as_float((u).x << 16); \
  a1 += __uint_as_float((u).x & 0xFFFF0000u); \
  a2 += __uint_as_float((u).y << 16); \
  a3 += __uint_as_float((u).y & 0xFFFF0000u); \
  a4 += __uint_as_float((u).z << 16); \
  a5 += __uint_as_float((u).z & 0xFFFF0000u); \
  a6 += __uint_as_float((u).w << 16); \
  a7 += __uint_as_float((u).w & 0xFFFF0000u);

__device__ __forceinline__ unsigned packbf(float lo, float hi) {
  return (unsigned)f2bf(lo) | ((unsigned)f2bf(hi) << 16);
}

// g = bf16( dis[i] * relu( dis[i]*(sum y1[src] + y1[i]) + b1 ) ).  Octet/node.
__global__ __launch_bounds__(256) void k_agg1(const unsigned short* __restrict__ y1b, const unsigned* __restrict__ rpd,
                                              const int* __restrict__ csrc, const float* __restrict__ dis,
                                              const float* __restrict__ b1, unsigned short* __restrict__ gb, int n) {
  int i = blockIdx.x * 32 + (threadIdx.x >> 3);
  if (i >= n) return;
  int fl = (threadIdx.x & 7) << 3;         // feature slice start (8 bf16 = 16B)
  float di = dis[i];                       // hoisted: independent loads overlap the gather
  float4 bb0 = *(const float4*)&b1[fl];
  float4 bb1 = *(const float4*)&b1[fl + 4];
  const uint4 us = *(const uint4*)&y1b[(i << 6) + fl];   // self term
  float a0 = __uint_as_float(us.x << 16);
  float a1 = __uint_as_float(us.x & 0xFFFF0000u);
  float a2 = __uint_as_float(us.y << 16);
  float a3 = __uint_as_float(us.y & 0xFFFF0000u);
  float a4 = __uint_as_float(us.z << 16);
  float a5 = __uint_as_float(us.z & 0xFFFF0000u);
  float a6 = __uint_as_float(us.w << 16);
  float a7 = __uint_as_float(us.w & 0xFFFF0000u);
  unsigned rd = rpd[i];
  int lo = (int)(rd >> 11), hi = lo + (int)(rd & 2047u);
  int e = lo;
  int s0, s1, s2, s3;
  if (e + 4 <= hi) { s0 = csrc[e]; s1 = csrc[e + 1]; s2 = csrc[e + 2]; s3 = csrc[e + 3]; }
  for (; e + 8 <= hi; e += 4) {
    uint4 u0 = *(const uint4*)&y1b[(s0 << 6) + fl];
    uint4 u1 = *(const uint4*)&y1b[(s1 << 6) + fl];
    uint4 u2 = *(const uint4*)&y1b[(s2 << 6) + fl];
    uint4 u3 = *(const uint4*)&y1b[(s3 << 6) + fl];
    s0 = csrc[e + 4]; s1 = csrc[e + 5]; s2 = csrc[e + 6]; s3 = csrc[e + 7];
    ACC8(u0) ACC8(u1) ACC8(u2) ACC8(u3)
  }
  if (e + 4 <= hi) {
    uint4 u0 = *(const uint4*)&y1b[(s0 << 6) + fl];
    uint4 u1 = *(const uint4*)&y1b[(s1 << 6) + fl];
    uint4 u2 = *(const uint4*)&y1b[(s2 << 6) + fl];
    uint4 u3 = *(const uint4*)&y1b[(s3 << 6) + fl];
    ACC8(u0) ACC8(u1) ACC8(u2) ACC8(u3)
    e += 4;
  }
  for (; e < hi; ++e) {
    int s = csrc[e];
    uint4 u = *(const uint4*)&y1b[(s << 6) + fl];
    ACC8(u)
  }
  uint4 o;
  o.x = packbf(di * fmaxf(fmaf(di, a0, bb0.x), 0.f), di * fmaxf(fmaf(di, a1, bb0.y), 0.f));
  o.y = packbf(di * fmaxf(fmaf(di, a2, bb0.z), 0.f), di * fmaxf(fmaf(di, a3, bb0.w), 0.f));
  o.z = packbf(di * fmaxf(fmaf(di, a4, bb1.x), 0.f), di * fmaxf(fmaf(di, a5, bb1.y), 0.f));
  o.w = packbf(di * fmaxf(fmaf(di, a6, bb1.z), 0.f), di * fmaxf(fmaf(di, a7, bb1.w), 0.f));
  *(uint4*)&gb[(i << 6) + fl] = o;
}

// FUSED hop2 + output GEMM:  ah = bf16( dis[i] * (sum g[src] + g[i]) ) -> LDS,
// then out = ah @ W2 + b2 via MFMA (bit-identical to the unfused version: ah is
// bf16-rounded before the MFMA).  32 nodes/block, 4 waves.
__global__ __launch_bounds__(256) void k_agg2(const unsigned short* __restrict__ gb, const unsigned* __restrict__ rpd,
                                              const int* __restrict__ csrc, const float* __restrict__ dis,
                                              const unsigned short* __restrict__ Wt2b, const float* __restrict__ b2,
                                              float* __restrict__ out, int n) {
  __shared__ unsigned short Ws[48 * 72];
  __shared__ unsigned short ahs[32 * 72];
  int t = threadIdx.x;
  int nodeBase = blockIdx.x * 32;
  // stage W2 (bf16 padded [48][64]) into LDS; in flight during the gather phase
  for (int id = t; id < 48 * 8; id += 256) {
    int c = id >> 3, kc = id & 7;
    *(short8*)&Ws[c * 72 + kc * 8] = *(const short8*)&Wt2b[c * NH + kc * 8];
  }
  int i = nodeBase + (t >> 3);
  int fl = (t & 7) << 3;
  if (i < n) {
    float di = dis[i];
    const uint4 us = *(const uint4*)&gb[(i << 6) + fl];
    float a0 = __uint_as_float(us.x << 16);
    float a1 = __uint_as_float(us.x & 0xFFFF0000u);
    float a2 = __uint_as_float(us.y << 16);
    float a3 = __uint_as_float(us.y & 0xFFFF0000u);
    float a4 = __uint_as_float(us.z << 16);
    float a5 = __uint_as_float(us.z & 0xFFFF0000u);
    float a6 = __uint_as_float(us.w << 16);
    float a7 = __uint_as_float(us.w & 0xFFFF0000u);
    unsigned rd = rpd[i];
    int lo = (int)(rd >> 11), hi = lo + (int)(rd & 2047u);
    int e = lo;
    int s0, s1, s2, s3;
    if (e + 4 <= hi) { s0 = csrc[e]; s1 = csrc[e + 1]; s2 = csrc[e + 2]; s3 = csrc[e + 3]; }
    for (; e + 8 <= hi; e += 4) {
      uint4 u0 = *(const uint4*)&gb[(s0 << 6) + fl];
      uint4 u1 = *(const uint4*)&gb[(s1 << 6) + fl];
      uint4 u2 = *(const uint4*)&gb[(s2 << 6) + fl];
      uint4 u3 = *(const uint4*)&gb[(s3 << 6) + fl];
      s0 = csrc[e + 4]; s1 = csrc[e + 5]; s2 = csrc[e + 6]; s3 = csrc[e + 7];
      ACC8(u0) ACC8(u1) ACC8(u2) ACC8(u3)
    }
    if (e + 4 <= hi) {
      uint4 u0 = *(const uint4*)&gb[(s0 << 6) + fl];
      uint4 u1 = *(const uint4*)&gb[(s1 << 6) + fl];
      uint4 u2 = *(const uint4*)&gb[(s2 << 6) + fl];
      uint4 u3 = *(const uint4*)&gb[(s3 << 6) + fl];
      ACC8(u0) ACC8(u1) ACC8(u2) ACC8(u3)
      e += 4;
    }
    for (; e < hi; ++e) {
      int s = csrc[e];
      uint4 u = *(const uint4*)&gb[(s << 6) + fl];
      ACC8(u)
    }
    uint4 o;
    o.x = packbf(di * a0, di * a1);
    o.y = packbf(di * a2, di * a3);
    o.z = packbf(di * a4, di * a5);
    o.w = packbf(di * a6, di * a7);
    *(uint4*)&ahs[(t >> 3) * 72 + fl] = o;
  }
  __syncthreads();
  int w = t >> 6, lane = t & 63;
  int m = lane & 15, quad = lane >> 4;
  if (w < 3) {                              // 3 waves cover 48 padded cols
#pragma unroll
    for (int mt = 0; mt < 2; ++mt) {        // 2 m-tiles of 16 nodes
      float4v acc = {0.f, 0.f, 0.f, 0.f};
#pragma unroll
      for (int ks = 0; ks < 2; ++ks) {
        short8 a = *(const short8*)&ahs[(mt * 16 + m) * 72 + ks * 32 + quad * 8];
        short8 b = *(const short8*)&Ws[(w * 16 + m) * 72 + ks * 32 + quad * 8];
        acc = __builtin_amdgcn_mfma_f32_16x16x32_bf16(a, b, acc, 0, 0, 0);
      }
      int col = w * 16 + m;
      if (col < NC) {
        float bias = b2[col];
#pragma unroll
        for (int r = 0; r < 4; ++r) {
          int node = nodeBase + mt * 16 + quad * 4 + r;
          if (node < n) out[node * NC + col] = acc[r] + bias;
        }
      }
    }
  }
}

extern "C" void kernel_launch(void* const* d_in, const int* in_sizes, int n_in,
                              void* d_out, int out_size, void* d_ws, size_t ws_size,
                              hipStream_t stream) {
  const float* x  = (const float*)d_in[0];
  const int*   ei = (const int*)d_in[1];
  const float* W1 = (const float*)d_in[2];
  const float* b1 = (const float*)d_in[3];
  const float* W2 = (const float*)d_in[4];
  const float* b2 = (const float*)d_in[5];
  float* out = (float*)d_out;
  int n  = in_sizes[0] / NF;    // 100000
  int nE = in_sizes[1] / 2;     // 1600000
  const int* src = ei;
  const int* dst = ei + nE;

  char* ws = (char*)d_ws;
  float*    dis  = (float*)(ws + 0);                   // 400 KB
  unsigned* rpd  = (unsigned*)(ws + 400000);           // 400 KB (start<<11 | deg)
  int*      gcur = (int*)(ws + 800000);                // 98 ints
  unsigned short* Wt1b = (unsigned short*)(ws + 800512);   // 16 KB
  unsigned short* Wt2b = (unsigned short*)(ws + 816896);   // 6 KB
  int*      csrc = (int*)(ws + 823296);                // 98*20480*4 = 8,028,160 B
  unsigned short* y1b = (unsigned short*)(ws + 8851456);   // 12.8 MB
  unsigned short* gb  = (unsigned short*)(ws + 21651456);  // 12.8 MB
  unsigned* binned = (unsigned*)(ws + 21651456);       // 8.03 MB, overlays gb (dead before agg1)

  (void)hipMemsetAsync(gcur, 0, NB * 4, stream);

  int nbin = (nE + BIN_T - 1) / BIN_T;                 // 196
  int nprep = (NF * NH + 48 * NH + 255) / 256;         // 44
  k_bin  <<<nbin + nprep, 256, 0, stream>>>(src, dst, gcur, binned, W1, W2, Wt1b, Wt2b, nE, nbin);
  k_fillb<<<NB, 1024, 0, stream>>>(binned, gcur, rpd, dis, csrc, n);
  k_xw   <<<n / 16, 256, 0, stream>>>(x, Wt1b, dis, y1b, n);
  k_agg1 <<<(n + 31) / 32, 256, 0, stream>>>(y1b, rpd, csrc, dis, b1, gb, n);
  k_agg2 <<<(n + 31) / 32, 256, 0, stream>>>(gb, rpd, csrc, dis, Wt2b, b2, out, n);
}